// Round 7
// baseline (160.967 us; speedup 1.0000x reference)
//
#include <hip/hip_runtime.h>
#include <math.h>

#define DD 2048
#define EE 64
#define KQ 32
#define TOKTILE 512
#define KSPLIT 8

// ---------------- K1: gate GEMM, K-split partials ----------------
// 256 thr (4 waves), tile 512 tok x 64 exp x 256 k. Thread: 16 tok x 8 exp
// (acc 128 VGPR). x and w both staged in LDS (no SMEM in the hot loop).
// Per k per thread: 4 x-b128 + 2 w-b128 + 128 FMA -> LDS demand ~96 B/cyc/CU
// vs 85 ceiling -> ~88% VALU ceiling. Reg-staged prefetch of chunk+1 issued at
// compute start (8192-cyc chunk hides HBM latency). fmaf chain ascending k
// over 256 -> partial bitwise-identical to the passing version.
__global__ __launch_bounds__(256, 1) void sr_gemm(
    const float* __restrict__ x, const float* __restrict__ wg,
    float* __restrict__ partial, int N)
{
  __shared__ float xs[KQ][TOKTILE];  // 64 KB, swizzled: (k,t) at t ^ 16*((k>>2)&3)
  __shared__ float wsh[KQ][EE];      // 8 KB
  const int ntiles = N / TOKTILE;    // 32
  const int tt = blockIdx.x % ntiles;
  const int kc = blockIdx.x / ntiles;
  const int kblk = DD / KSPLIT;      // 256
  const int nchunk = kblk / KQ;      // 8
  const int k0 = kc * kblk;
  const int t0 = tt * TOKTILE;
  const int tid = threadIdx.x;
  const int tq = tid >> 3;           // 0..31: tokens 4tq + 128g + j
  const int te = tid & 7;            // experts 8te..8te+7
  // x loader: 16 passes x 32 rows; 8 threads/row, 128B contiguous per row
  const int lrow = tid >> 3;
  const int lc4 = (tid & 7) * 4;
  const int lswz = 16 * (tid & 3);   // == 16*(((lc4+j)>>2)&3)
  // w loader: expert tid>>2, k-octet (tid&3)*8
  const int we = tid >> 2;
  const int wkq = (tid & 3) * 8;

  float acc[16][8];
#pragma unroll
  for (int r = 0; r < 16; ++r)
#pragma unroll
    for (int c = 0; c < 8; ++c) acc[r][c] = 0.f;

  float4 vx[16];
  float4 vw0, vw1;

  // prologue: load chunk 0
#pragma unroll
  for (int p = 0; p < 16; ++p)
    vx[p] = *reinterpret_cast<const float4*>(
        &x[(size_t)(t0 + p * 32 + lrow) * DD + k0 + lc4]);
  vw0 = *reinterpret_cast<const float4*>(&wg[(size_t)we * DD + k0 + wkq]);
  vw1 = *reinterpret_cast<const float4*>(&wg[(size_t)we * DD + k0 + wkq + 4]);

  for (int ch = 0; ch < nchunk; ++ch) {
    __syncthreads();  // previous chunk's readers done
#pragma unroll
    for (int p = 0; p < 16; ++p) {
      const int srow = (p * 32 + lrow) ^ lswz;
      xs[lc4 + 0][srow] = vx[p].x;
      xs[lc4 + 1][srow] = vx[p].y;
      xs[lc4 + 2][srow] = vx[p].z;
      xs[lc4 + 3][srow] = vx[p].w;
    }
    wsh[wkq + 0][we] = vw0.x; wsh[wkq + 1][we] = vw0.y;
    wsh[wkq + 2][we] = vw0.z; wsh[wkq + 3][we] = vw0.w;
    wsh[wkq + 4][we] = vw1.x; wsh[wkq + 5][we] = vw1.y;
    wsh[wkq + 6][we] = vw1.z; wsh[wkq + 7][we] = vw1.w;
    __syncthreads();  // LDS ready
    if (ch + 1 < nchunk) {  // prefetch next chunk; hidden under compute
      const int kb = k0 + (ch + 1) * KQ;
#pragma unroll
      for (int p = 0; p < 16; ++p)
        vx[p] = *reinterpret_cast<const float4*>(
            &x[(size_t)(t0 + p * 32 + lrow) * DD + kb + lc4]);
      vw0 = *reinterpret_cast<const float4*>(&wg[(size_t)we * DD + kb + wkq]);
      vw1 = *reinterpret_cast<const float4*>(&wg[(size_t)we * DD + kb + wkq + 4]);
    }
#pragma unroll
    for (int k = 0; k < KQ; ++k) {
      const int sk = 16 * ((k >> 2) & 3);
      float xv[16], wv[8];
      *reinterpret_cast<float4*>(&xv[0]) =
          *reinterpret_cast<const float4*>(&xs[k][(4 * tq + 0) ^ sk]);
      *reinterpret_cast<float4*>(&xv[4]) =
          *reinterpret_cast<const float4*>(&xs[k][(4 * tq + 128) ^ sk]);
      *reinterpret_cast<float4*>(&xv[8]) =
          *reinterpret_cast<const float4*>(&xs[k][(4 * tq + 256) ^ sk]);
      *reinterpret_cast<float4*>(&xv[12]) =
          *reinterpret_cast<const float4*>(&xs[k][(4 * tq + 384) ^ sk]);
      *reinterpret_cast<float4*>(&wv[0]) =
          *reinterpret_cast<const float4*>(&wsh[k][8 * te]);
      *reinterpret_cast<float4*>(&wv[4]) =
          *reinterpret_cast<const float4*>(&wsh[k][8 * te + 4]);
#pragma unroll
      for (int r = 0; r < 16; ++r)
#pragma unroll
        for (int c = 0; c < 8; ++c) acc[r][c] = fmaf(xv[r], wv[c], acc[r][c]);
    }
  }
  // store partial[kc][e][t]: 8 lines of 128B per instr, fully covered
#pragma unroll
  for (int c = 0; c < 8; ++c) {
    const int e = 8 * te + c;
#pragma unroll
    for (int g = 0; g < 4; ++g) {
      const float4 v = make_float4(acc[4 * g + 0][c], acc[4 * g + 1][c],
                                   acc[4 * g + 2][c], acc[4 * g + 3][c]);
      *reinterpret_cast<float4*>(
          &partial[((size_t)kc * EE + e) * N + t0 + 4 * tq + 128 * g]) = v;
    }
  }
}

// ---------------- K2: cross-ksplit reduction -> logits[e][t] (+zero counts) ----
// f64 sum in fixed c-order: bitwise-identical to the passing path.
__global__ __launch_bounds__(256) void sr_reduce(
    const float* __restrict__ partial, float* __restrict__ logits,
    int* __restrict__ counts, int N, int ksplit)
{
  if (blockIdx.x == 0 && threadIdx.x < EE) counts[threadIdx.x] = 0;
  const int i4 = blockIdx.x * 256 + threadIdx.x;   // over EE*N/4
  const size_t base = (size_t)i4 * 4;
  if (base >= (size_t)EE * N) return;
  const size_t cs = (size_t)EE * N;
  double s0 = 0.0, s1 = 0.0, s2 = 0.0, s3 = 0.0;
  for (int c = 0; c < ksplit; ++c) {
    const float4 v = *reinterpret_cast<const float4*>(&partial[c * cs + base]);
    s0 += (double)v.x; s1 += (double)v.y; s2 += (double)v.z; s3 += (double)v.w;
  }
  *reinterpret_cast<float4*>(&logits[base]) =
      make_float4((float)s0, (float)s1, (float)s2, (float)s3);
}

// ---------------- K3: per-token softmax/argmax (128 tok / 256 thr blocks) ----
__global__ __launch_bounds__(256) void sr_softmax(
    const float* __restrict__ logits, float* __restrict__ dout,
    float* __restrict__ ws_w, int* __restrict__ ws_idx,
    int* __restrict__ counts, float* __restrict__ probsum, int N)
{
  __shared__ float lp[128][EE + 1];
  __shared__ float psq[4][EE];
  const int tid = threadIdx.x;
  const int t0 = blockIdx.x * 128;
  if (tid < 128) {
    const int t = t0 + tid;
    float l[EE];
    float maxv = -3.0e38f;
    int arg = 0;
#pragma unroll
    for (int e = 0; e < EE; ++e) {
      l[e] = logits[(size_t)e * N + t];
      if (l[e] > maxv) { maxv = l[e]; arg = e; }  // strict > : first max wins
    }
    float s = 0.f;
#pragma unroll
    for (int e = 0; e < EE; ++e) {
      const float ex = __expf(l[e] - maxv);
      lp[tid][e] = ex;
      s += ex;
    }
    const float inv = 1.0f / s;
    const float w = inv;  // exp(0)/sum
#pragma unroll
    for (int e = 0; e < EE; ++e) lp[tid][e] *= inv;
    dout[t] = w;
    dout[N + t] = (float)arg;
    ws_w[t] = w;
    ws_idx[t] = arg;
    atomicAdd(&counts[arg], 1);
  }
  __syncthreads();
  const int e = tid & 63, q = tid >> 6;
  float ps = 0.f;
  for (int r = 0; r < 32; ++r) ps += lp[q * 32 + r][e];
  psq[q][e] = ps;
  __syncthreads();
  if (tid < 64) {
    const float tot = ((psq[0][tid] + psq[1][tid]) + psq[2][tid]) + psq[3][tid];
    probsum[(size_t)blockIdx.x * EE + tid] = tot;
  }
}

// ---------------- K4: stats, aux loss, mode ----------------
__global__ __launch_bounds__(256) void sr_stats(
    const float* __restrict__ probsum, const int* __restrict__ counts,
    float* __restrict__ dout, int* __restrict__ header,
    int N, int nblocks, int cap)
{
  __shared__ double dq[4][EE];
  __shared__ double mean_s[EE];
  __shared__ int cnt_s[EE];
  const int tid = threadIdx.x;
  const int e = tid & 63, q = tid >> 6;
  const int per = nblocks / 4;
  double ps = 0.0;
  for (int b = q * per; b < (q + 1) * per; ++b)
    ps += (double)probsum[(size_t)b * EE + e];
  dq[q][e] = ps;
  __syncthreads();
  if (tid < 64) {
    const double tot = ((dq[0][tid] + dq[1][tid]) + dq[2][tid]) + dq[3][tid];
    const int cnt = counts[tid];
    dout[2 * N + tid] = (float)cnt;
    mean_s[tid] = tot / (double)N;
    cnt_s[tid] = cnt;
  }
  __syncthreads();
  if (tid == 0) {
    double aux = 0.0;
    int nover = 0, e1 = -1;
    for (int i = 0; i < EE; ++i) {
      aux += ((double)cnt_s[i] / (double)N) * mean_s[i];
      if (cnt_s[i] > cap) { if (nover == 0) e1 = i; ++nover; }
    }
    dout[2 * N + EE] = (float)(aux * (double)EE);
    header[0] = (nover >= 2) ? 2 : nover;
    header[1] = e1;
  }
}

// ---------------- K5: exact top-cap selection (mode==1) ----------------
__device__ __forceinline__ int sr_bsum(int c, int red[][16], int pc, int tid) {
#pragma unroll
  for (int off = 32; off > 0; off >>= 1) c += __shfl_down(c, off, 64);
  if ((tid & 63) == 0) red[pc & 1][tid >> 6] = c;
  __syncthreads();
  int s = 0;
#pragma unroll
  for (int i = 0; i < 16; ++i) s += red[pc & 1][i];
  return s;
}

__global__ __launch_bounds__(1024) void sr_select(
    const float* __restrict__ ws_w, const int* __restrict__ ws_idx,
    int* __restrict__ header, int N, int cap)
{
  __shared__ int red[2][16];
  const int tid = threadIdx.x;
  const int mode = header[0];
  if (mode != 1) {
    if (tid == 0) { header[2] = 0; header[3] = N; }
    return;
  }
  const int e1 = header[1];
  unsigned mb[16];  // PER = N/1024 = 16, cached in VGPRs
  const int PER = N / 1024;
  for (int r = 0; r < 16; ++r) {
    unsigned b = 0u;
    if (r < PER) {
      const int i = tid + r * 1024;
      if (ws_idx[i] == e1) b = __float_as_uint(ws_w[i]);
    }
    mb[r] = b;
  }
  int pc = 0;
  // w = 1/softmax_sum in [1/64, 1): search bits in [0x3C000000, 0x3F800000)
  unsigned lo = 0x3C000000u, hi = 0x3F800000u;
  while (hi - lo > 1u) {
    const unsigned mid = lo + ((hi - lo) >> 1);
    int c = 0;
#pragma unroll
    for (int r = 0; r < 16; ++r) c += (mb[r] >= mid);
    const int tot = sr_bsum(c, red, pc++, tid);
    if (tot >= cap) lo = mid; else hi = mid;
  }
  int cge = 0, cgt = 0;
#pragma unroll
  for (int r = 0; r < 16; ++r) {
    cge += (mb[r] >= lo);
    cgt += (mb[r] > lo);
  }
  const int tot_ge = sr_bsum(cge, red, pc++, tid);
  const int tot_gt = sr_bsum(cgt, red, pc++, tid);
  const int quota = cap - tot_gt;
  int idx_thr = N - 1;
  if (tot_ge - tot_gt > quota) {
    // tie at tau: keep the quota lowest-index equals (lax.top_k tie-break)
    int l2 = -1, h2 = N - 1;
    while (h2 - l2 > 1) {
      const int mid = (l2 + h2) >> 1;
      int c = 0;
#pragma unroll
      for (int r = 0; r < 16; ++r) {
        const int i = tid + r * 1024;
        c += (mb[r] == lo && mb[r] != 0u && i <= mid) ? 1 : 0;
      }
      const int tot = sr_bsum(c, red, pc++, tid);
      if (tot >= quota) h2 = mid; else l2 = mid;
    }
    idx_thr = h2;
  }
  if (tid == 0) { header[2] = (int)lo; header[3] = idx_thr; }
}

// ---------------- K6: apply capacity filter ----------------
__global__ __launch_bounds__(256) void sr_apply(
    const float* __restrict__ ws_w, const int* __restrict__ ws_idx,
    const int* __restrict__ header, float* __restrict__ dout, int N)
{
  const int i = blockIdx.x * 256 + threadIdx.x;
  if (i >= N) return;
  const int mode = header[0];
  const float w = ws_w[i];
  float out = w;
  if (mode == 2) {
    out = 0.f;
  } else if (mode == 1) {
    const int e1 = header[1];
    const unsigned tau = (unsigned)header[2];
    const int ithr = header[3];
    const unsigned b = __float_as_uint(w);
    const bool keep = (ws_idx[i] == e1) && (b > tau || (b == tau && i <= ithr));
    out = keep ? w : 0.f;
  }
  dout[i] = out;
}

// ---------------- launch ----------------
extern "C" void kernel_launch(void* const* d_in, const int* in_sizes, int n_in,
                              void* d_out, int out_size, void* d_ws, size_t ws_size,
                              hipStream_t stream)
{
  const float* x = (const float*)d_in[0];
  const float* wg = (const float*)d_in[1];
  const int N = in_sizes[0] / DD;  // 16384
  float* dout = (float*)d_out;
  float* wsf = (float*)d_ws;

  // ws layout (floats):
  // [ws_w N][ws_idx N][counts 64][probsum (N/128)*64][header 16][logits EE*N][partial ...]
  float* ws_w = wsf;
  int* ws_idx = (int*)(wsf + N);
  int* counts = (int*)(wsf + 2 * (size_t)N);
  float* probsum = wsf + 2 * (size_t)N + EE;
  const int nblocks_sm = N / 128;
  int* header = (int*)(wsf + 2 * (size_t)N + EE + (size_t)nblocks_sm * EE);
  float* logits = wsf + 2 * (size_t)N + EE + (size_t)nblocks_sm * EE + 16;
  float* partial = logits + (size_t)EE * N;
  const int cap = (int)((double)N * 1.25 / (double)EE);  // 320

  sr_gemm<<<(N / TOKTILE) * KSPLIT, 256, 0, stream>>>(x, wg, partial, N);
  sr_reduce<<<(EE * N / 4 + 255) / 256, 256, 0, stream>>>(partial, logits, counts, N, KSPLIT);
  sr_softmax<<<N / 128, 256, 0, stream>>>(logits, dout, ws_w, ws_idx, counts, probsum, N);
  sr_stats<<<1, 256, 0, stream>>>(probsum, counts, dout, header, N, nblocks_sm, cap);
  sr_select<<<1, 1024, 0, stream>>>(ws_w, ws_idx, header, N, cap);
  sr_apply<<<(N + 255) / 256, 256, 0, stream>>>(ws_w, ws_idx, header, dout, N);
}

// Round 8
// 155.459 us; speedup vs baseline: 1.0354x; 1.0354x over previous
//
#include <hip/hip_runtime.h>
#include <math.h>

#define DD 2048
#define EE 64
#define KQ 32
#define TOKTILE 128
#define KSPLIT 8

// ---------------- K1: gate GEMM, K-split partials ----------------
// R5 geometry (proven 81us): 256 thr, tile 128 tok x 64 exp x 256 k, thread
// 4 tok x 8 exp, 4 blocks/CU. New: register prefetch of chunk+1 issued after
// the LDS-ready barrier -> global latency hides under the 32-k FMA block;
// between barriers only LDS writes remain. fmaf k-chain unchanged -> partial
// bitwise-identical.
__global__ __launch_bounds__(256, 4) void sr_gemm(
    const float* __restrict__ x, const float* __restrict__ wg,
    float* __restrict__ partial, int* __restrict__ counts, int N)
{
  __shared__ float xs[KQ][TOKTILE];  // 16 KB, swizzled (t ^ 8*((k>>2)&3))
  __shared__ float wsh[KQ][EE];      // 8 KB
  if (blockIdx.x == 0 && threadIdx.x < EE) counts[threadIdx.x] = 0;
  const int ntiles = N / TOKTILE;    // 128
  const int tt = blockIdx.x % ntiles;
  const int kc = blockIdx.x / ntiles;
  const int kblk = DD / KSPLIT;      // 256
  const int nchunk = kblk / KQ;      // 8
  const int k0 = kc * kblk;
  const int t0 = tt * TOKTILE;
  const int tid = threadIdx.x;
  const int ti = tid & 31;           // token quad 4ti..4ti+3
  const int tj = tid >> 5;           // expert octet 8tj..8tj+7 (2 per wave -> broadcast)
  // x loader: 4 passes x 32 rows, 8 thr/row
  const int srowb = tid >> 3;        // 0..31
  const int c4 = (tid & 7) * 4;
  const int swz = 8 * (tid & 3);     // == 8*(((c4+j)>>2)&3)
  // w loader
  const int we = tid >> 2;
  const int wkq = (tid & 3) * 8;

  float acc[4][8];
#pragma unroll
  for (int r = 0; r < 4; ++r)
#pragma unroll
    for (int c = 0; c < 8; ++c) acc[r][c] = 0.f;

  float4 vx[4], vw0, vw1;
  // prologue: chunk 0 into regs
#pragma unroll
  for (int p = 0; p < 4; ++p)
    vx[p] = *reinterpret_cast<const float4*>(
        &x[(size_t)(t0 + p * 32 + srowb) * DD + k0 + c4]);
  vw0 = *reinterpret_cast<const float4*>(&wg[(size_t)we * DD + k0 + wkq]);
  vw1 = *reinterpret_cast<const float4*>(&wg[(size_t)we * DD + k0 + wkq + 4]);

  for (int ch = 0; ch < nchunk; ++ch) {
    __syncthreads();  // previous chunk's readers done
#pragma unroll
    for (int p = 0; p < 4; ++p) {
      const int srow = (p * 32 + srowb) ^ swz;
      xs[c4 + 0][srow] = vx[p].x;
      xs[c4 + 1][srow] = vx[p].y;
      xs[c4 + 2][srow] = vx[p].z;
      xs[c4 + 3][srow] = vx[p].w;
    }
    wsh[wkq + 0][we] = vw0.x; wsh[wkq + 1][we] = vw0.y;
    wsh[wkq + 2][we] = vw0.z; wsh[wkq + 3][we] = vw0.w;
    wsh[wkq + 4][we] = vw1.x; wsh[wkq + 5][we] = vw1.y;
    wsh[wkq + 6][we] = vw1.z; wsh[wkq + 7][we] = vw1.w;
    __syncthreads();  // LDS ready
    if (ch + 1 < nchunk) {  // prefetch next chunk; latency hidden by compute
      const int kb = k0 + (ch + 1) * KQ;
#pragma unroll
      for (int p = 0; p < 4; ++p)
        vx[p] = *reinterpret_cast<const float4*>(
            &x[(size_t)(t0 + p * 32 + srowb) * DD + kb + c4]);
      vw0 = *reinterpret_cast<const float4*>(&wg[(size_t)we * DD + kb + wkq]);
      vw1 = *reinterpret_cast<const float4*>(&wg[(size_t)we * DD + kb + wkq + 4]);
    }
#pragma unroll
    for (int k = 0; k < KQ; ++k) {
      const int sk = 8 * ((k >> 2) & 3);
      float xv[4], wv[8];
      *reinterpret_cast<float4*>(&xv[0]) =
          *reinterpret_cast<const float4*>(&xs[k][(4 * ti) ^ sk]);
      *reinterpret_cast<float4*>(&wv[0]) =
          *reinterpret_cast<const float4*>(&wsh[k][8 * tj]);
      *reinterpret_cast<float4*>(&wv[4]) =
          *reinterpret_cast<const float4*>(&wsh[k][8 * tj + 4]);
#pragma unroll
      for (int r = 0; r < 4; ++r)
#pragma unroll
        for (int c = 0; c < 8; ++c) acc[r][c] = fmaf(xv[r], wv[c], acc[r][c]);
    }
  }
  // partial[kc][e][t]: float4 over tokens, coalesced
#pragma unroll
  for (int c = 0; c < 8; ++c) {
    const int e = 8 * tj + c;
    const float4 v = make_float4(acc[0][c], acc[1][c], acc[2][c], acc[3][c]);
    *reinterpret_cast<float4*>(&partial[((size_t)kc * EE + e) * N + t0 + 4 * ti]) = v;
  }
}

// ---------------- K2: fused ksplit-reduce + softmax/argmax (64 tok/block) ----
// Phase A reproduces sr_reduce bitwise: s = sum_{c asc} (double)partial[c][e][t].
__global__ __launch_bounds__(256) void sr_redsm(
    const float* __restrict__ partial, float* __restrict__ dout,
    float* __restrict__ ws_w, int* __restrict__ ws_idx,
    int* __restrict__ counts, float* __restrict__ probsum, int N)
{
  __shared__ float lp[64][EE + 1];
  __shared__ float psq[4][EE];
  const int tid = threadIdx.x;
  const int t0 = blockIdx.x * 64;
  const size_t cs = (size_t)EE * N;
  // phase A: 16 (e,t) f64 sums per thread; waves read 256B contiguous runs
  {
    const int t = tid & 63;
    const int eq = tid >> 6;  // 0..3
#pragma unroll
    for (int eo = 0; eo < 16; ++eo) {
      const int e = eq * 16 + eo;
      double s = 0.0;
      for (int c = 0; c < KSPLIT; ++c)
        s += (double)partial[c * cs + (size_t)e * N + t0 + t];
      lp[t][e] = (float)s;
    }
  }
  __syncthreads();
  // phase B: per-token softmax/argmax
  if (tid < 64) {
    const int t = t0 + tid;
    float l[EE];
    float maxv = -3.0e38f;
    int arg = 0;
#pragma unroll
    for (int e = 0; e < EE; ++e) {
      l[e] = lp[tid][e];
      if (l[e] > maxv) { maxv = l[e]; arg = e; }  // strict > : first max wins
    }
    float s = 0.f;
#pragma unroll
    for (int e = 0; e < EE; ++e) {
      const float ex = __expf(l[e] - maxv);
      l[e] = ex;
      s += ex;
    }
    const float inv = 1.0f / s;
    const float w = inv;  // exp(0)/sum
#pragma unroll
    for (int e = 0; e < EE; ++e) lp[tid][e] = l[e] * inv;
    dout[t] = w;
    dout[N + t] = (float)arg;
    ws_w[t] = w;
    ws_idx[t] = arg;
    atomicAdd(&counts[arg], 1);
  }
  __syncthreads();
  // phase C: per-block prob sums (deterministic order)
  {
    const int e = tid & 63, q = tid >> 6;
    float ps = 0.f;
#pragma unroll
    for (int r = 0; r < 16; ++r) ps += lp[q * 16 + r][e];
    psq[q][e] = ps;
  }
  __syncthreads();
  if (tid < 64) {
    const float tot = ((psq[0][tid] + psq[1][tid]) + psq[2][tid]) + psq[3][tid];
    probsum[(size_t)blockIdx.x * EE + tid] = tot;
  }
}

// ---------------- K3: stats, aux loss, mode ----------------
__global__ __launch_bounds__(256) void sr_stats(
    const float* __restrict__ probsum, const int* __restrict__ counts,
    float* __restrict__ dout, int* __restrict__ header,
    int N, int nblocks, int cap)
{
  __shared__ double dq[4][EE];
  __shared__ double mean_s[EE];
  __shared__ int cnt_s[EE];
  const int tid = threadIdx.x;
  const int e = tid & 63, q = tid >> 6;
  const int per = nblocks / 4;
  double ps = 0.0;
  for (int b = q * per; b < (q + 1) * per; ++b)
    ps += (double)probsum[(size_t)b * EE + e];
  dq[q][e] = ps;
  __syncthreads();
  if (tid < 64) {
    const double tot = ((dq[0][tid] + dq[1][tid]) + dq[2][tid]) + dq[3][tid];
    const int cnt = counts[tid];
    dout[2 * N + tid] = (float)cnt;
    mean_s[tid] = tot / (double)N;
    cnt_s[tid] = cnt;
  }
  __syncthreads();
  if (tid == 0) {
    double aux = 0.0;
    int nover = 0, e1 = -1;
    for (int i = 0; i < EE; ++i) {
      aux += ((double)cnt_s[i] / (double)N) * mean_s[i];
      if (cnt_s[i] > cap) { if (nover == 0) e1 = i; ++nover; }
    }
    dout[2 * N + EE] = (float)(aux * (double)EE);
    header[0] = (nover >= 2) ? 2 : nover;
    header[1] = e1;
  }
}

// ---------------- K4: exact top-cap selection (mode==1) ----------------
__device__ __forceinline__ int sr_bsum(int c, int red[][16], int pc, int tid) {
#pragma unroll
  for (int off = 32; off > 0; off >>= 1) c += __shfl_down(c, off, 64);
  if ((tid & 63) == 0) red[pc & 1][tid >> 6] = c;
  __syncthreads();
  int s = 0;
#pragma unroll
  for (int i = 0; i < 16; ++i) s += red[pc & 1][i];
  return s;
}

__global__ __launch_bounds__(1024) void sr_select(
    const float* __restrict__ ws_w, const int* __restrict__ ws_idx,
    int* __restrict__ header, int N, int cap)
{
  __shared__ int red[2][16];
  const int tid = threadIdx.x;
  const int mode = header[0];
  if (mode != 1) {
    if (tid == 0) { header[2] = 0; header[3] = N; }
    return;
  }
  const int e1 = header[1];
  unsigned mb[16];  // PER = N/1024 = 16, cached in VGPRs
  const int PER = N / 1024;
  for (int r = 0; r < 16; ++r) {
    unsigned b = 0u;
    if (r < PER) {
      const int i = tid + r * 1024;
      if (ws_idx[i] == e1) b = __float_as_uint(ws_w[i]);
    }
    mb[r] = b;
  }
  int pc = 0;
  // w = 1/softmax_sum in [1/64, 1): search bits in [0x3C000000, 0x3F800000)
  unsigned lo = 0x3C000000u, hi = 0x3F800000u;
  while (hi - lo > 1u) {
    const unsigned mid = lo + ((hi - lo) >> 1);
    int c = 0;
#pragma unroll
    for (int r = 0; r < 16; ++r) c += (mb[r] >= mid);
    const int tot = sr_bsum(c, red, pc++, tid);
    if (tot >= cap) lo = mid; else hi = mid;
  }
  int cge = 0, cgt = 0;
#pragma unroll
  for (int r = 0; r < 16; ++r) {
    cge += (mb[r] >= lo);
    cgt += (mb[r] > lo);
  }
  const int tot_ge = sr_bsum(cge, red, pc++, tid);
  const int tot_gt = sr_bsum(cgt, red, pc++, tid);
  const int quota = cap - tot_gt;
  int idx_thr = N - 1;
  if (tot_ge - tot_gt > quota) {
    // tie at tau: keep the quota lowest-index equals (lax.top_k tie-break)
    int l2 = -1, h2 = N - 1;
    while (h2 - l2 > 1) {
      const int mid = (l2 + h2) >> 1;
      int c = 0;
#pragma unroll
      for (int r = 0; r < 16; ++r) {
        const int i = tid + r * 1024;
        c += (mb[r] == lo && mb[r] != 0u && i <= mid) ? 1 : 0;
      }
      const int tot = sr_bsum(c, red, pc++, tid);
      if (tot >= quota) h2 = mid; else l2 = mid;
    }
    idx_thr = h2;
  }
  if (tid == 0) { header[2] = (int)lo; header[3] = idx_thr; }
}

// ---------------- K5: apply capacity filter ----------------
__global__ __launch_bounds__(256) void sr_apply(
    const float* __restrict__ ws_w, const int* __restrict__ ws_idx,
    const int* __restrict__ header, float* __restrict__ dout, int N)
{
  const int i = blockIdx.x * 256 + threadIdx.x;
  if (i >= N) return;
  const int mode = header[0];
  const float w = ws_w[i];
  float out = w;
  if (mode == 2) {
    out = 0.f;
  } else if (mode == 1) {
    const int e1 = header[1];
    const unsigned tau = (unsigned)header[2];
    const int ithr = header[3];
    const unsigned b = __float_as_uint(w);
    const bool keep = (ws_idx[i] == e1) && (b > tau || (b == tau && i <= ithr));
    out = keep ? w : 0.f;
  }
  dout[i] = out;
}

// ---------------- launch ----------------
extern "C" void kernel_launch(void* const* d_in, const int* in_sizes, int n_in,
                              void* d_out, int out_size, void* d_ws, size_t ws_size,
                              hipStream_t stream)
{
  const float* x = (const float*)d_in[0];
  const float* wg = (const float*)d_in[1];
  const int N = in_sizes[0] / DD;  // 16384
  float* dout = (float*)d_out;
  float* wsf = (float*)d_ws;

  // ws layout (floats):
  // [ws_w N][ws_idx N][counts 64][probsum (N/64)*64][header 16][partial ...]
  float* ws_w = wsf;
  int* ws_idx = (int*)(wsf + N);
  int* counts = (int*)(wsf + 2 * (size_t)N);
  float* probsum = wsf + 2 * (size_t)N + EE;
  const int nblocks_sm = N / 64;  // 256
  int* header = (int*)(wsf + 2 * (size_t)N + EE + (size_t)nblocks_sm * EE);
  float* partial = wsf + 2 * (size_t)N + EE + (size_t)nblocks_sm * EE + 16;
  const int cap = (int)((double)N * 1.25 / (double)EE);  // 320

  sr_gemm<<<(N / TOKTILE) * KSPLIT, 256, 0, stream>>>(x, wg, partial, counts, N);
  sr_redsm<<<N / 64, 256, 0, stream>>>(partial, dout, ws_w, ws_idx, counts, probsum, N);
  sr_stats<<<1, 256, 0, stream>>>(probsum, counts, dout, header, N, nblocks_sm, cap);
  sr_select<<<1, 1024, 0, stream>>>(ws_w, ws_idx, header, N, cap);
  sr_apply<<<(N + 255) / 256, 256, 0, stream>>>(ws_w, ws_idx, header, dout, N);
}

// Round 9
// 144.579 us; speedup vs baseline: 1.1133x; 1.0753x over previous
//
#include <hip/hip_runtime.h>
#include <math.h>

#define DD 2048
#define EE 64
#define KQ 32
#define TOKTILE 128

// ---------------- K1: gate GEMM, K-split partials (R5 verbatim, 81us) -------
// Tile: 128 tokens x 64 experts x 256 k per block. Thread tile 4 tok x 8 exp.
// xs is XOR-swizzled (t ^ 8*((k>>2)&3)); staging loads sit between the two
// barriers and are latency-hidden by 4 blocks/CU TLP.
__global__ __launch_bounds__(256, 4) void sr_gemm(
    const float* __restrict__ x, const float* __restrict__ wg,
    float* __restrict__ partial, int N, int ksplit)
{
  __shared__ float xs[KQ][TOKTILE];  // 16 KB, swizzled
  __shared__ float wsh[KQ][EE];      // 8 KB
  const int ntiles = N / TOKTILE;
  const int tt = blockIdx.x % ntiles;
  const int kc = blockIdx.x / ntiles;
  const int kblk = DD / ksplit;
  const int nchunk = kblk / KQ;
  const int k0 = kc * kblk;
  const int t0 = tt * TOKTILE;
  const int tid = threadIdx.x;
  const int ti = tid & 31;   // token quad: tokens 4*ti .. 4*ti+3
  const int tj = tid >> 5;   // expert octet: experts 8*tj .. 8*tj+7

  float acc[4][8];
#pragma unroll
  for (int r = 0; r < 4; ++r)
#pragma unroll
    for (int c = 0; c < 8; ++c) acc[r][c] = 0.f;

  // staging indices (x): 4 rounds cover 128 rows x 32 k
  const int srowbase = tid >> 3;          // 0..31
  const int c4 = (tid & 7) * 4;           // k quad base
  const int swz = 8 * (tid & 3);          // == 8 * (((c4+j)>>2) & 3)

  for (int ch = 0; ch < nchunk; ++ch) {
    const int kb = k0 + ch * KQ;
#pragma unroll
    for (int p = 0; p < 4; ++p) {
      const int row = p * 32 + srowbase;
      const float4 v = *reinterpret_cast<const float4*>(
          &x[(size_t)(t0 + row) * DD + kb + c4]);
      const int srow = row ^ swz;         // 2-way bank spread on writes
      xs[c4 + 0][srow] = v.x;
      xs[c4 + 1][srow] = v.y;
      xs[c4 + 2][srow] = v.z;
      xs[c4 + 3][srow] = v.w;
    }
    {
      const int e = tid >> 2;
      const int kq = (tid & 3) * 8;
      const float4 a = *reinterpret_cast<const float4*>(&wg[(size_t)e * DD + kb + kq]);
      const float4 b = *reinterpret_cast<const float4*>(&wg[(size_t)e * DD + kb + kq + 4]);
      wsh[kq + 0][e] = a.x; wsh[kq + 1][e] = a.y; wsh[kq + 2][e] = a.z; wsh[kq + 3][e] = a.w;
      wsh[kq + 4][e] = b.x; wsh[kq + 5][e] = b.y; wsh[kq + 6][e] = b.z; wsh[kq + 7][e] = b.w;
    }
    __syncthreads();
#pragma unroll 8
    for (int k = 0; k < KQ; ++k) {
      const int sk = 8 * ((k >> 2) & 3);
      float xv[4], wv[8];
      *reinterpret_cast<float4*>(&xv[0]) =
          *reinterpret_cast<const float4*>(&xs[k][(4 * ti) ^ sk]);
      *reinterpret_cast<float4*>(&wv[0]) = *reinterpret_cast<const float4*>(&wsh[k][8 * tj]);
      *reinterpret_cast<float4*>(&wv[4]) = *reinterpret_cast<const float4*>(&wsh[k][8 * tj + 4]);
#pragma unroll
      for (int r = 0; r < 4; ++r)
#pragma unroll
        for (int c = 0; c < 8; ++c) acc[r][c] = fmaf(xv[r], wv[c], acc[r][c]);
    }
    __syncthreads();
  }
  // partial[kc][e][t]: float4 over tokens, coalesced
#pragma unroll
  for (int c = 0; c < 8; ++c) {
    const int e = 8 * tj + c;
    const float4 v = make_float4(acc[0][c], acc[1][c], acc[2][c], acc[3][c]);
    *reinterpret_cast<float4*>(&partial[((size_t)kc * EE + e) * N + t0 + 4 * ti]) = v;
  }
}

// ---------------- K2: cross-ksplit reduction -> logits[e][t] (+zero counts) ----
// f64 sum in fixed c-order: bitwise-identical to the passing path.
__global__ __launch_bounds__(256) void sr_reduce(
    const float* __restrict__ partial, float* __restrict__ logits,
    int* __restrict__ counts, int N, int ksplit)
{
  if (blockIdx.x == 0 && threadIdx.x < EE) counts[threadIdx.x] = 0;
  const int i4 = blockIdx.x * 256 + threadIdx.x;   // over EE*N/4
  const size_t base = (size_t)i4 * 4;
  if (base >= (size_t)EE * N) return;
  const size_t cs = (size_t)EE * N;
  double s0 = 0.0, s1 = 0.0, s2 = 0.0, s3 = 0.0;
  for (int c = 0; c < ksplit; ++c) {
    const float4 v = *reinterpret_cast<const float4*>(&partial[c * cs + base]);
    s0 += (double)v.x; s1 += (double)v.y; s2 += (double)v.z; s3 += (double)v.w;
  }
  *reinterpret_cast<float4*>(&logits[base]) =
      make_float4((float)s0, (float)s1, (float)s2, (float)s3);
}

// ---------------- K3: per-token softmax/argmax (128 tok / 256 thr blocks) ----
__global__ __launch_bounds__(256) void sr_softmax(
    const float* __restrict__ logits, float* __restrict__ dout,
    float* __restrict__ ws_w, int* __restrict__ ws_idx,
    int* __restrict__ counts, float* __restrict__ probsum, int N)
{
  __shared__ float lp[128][EE + 1];
  __shared__ float psq[4][EE];
  const int tid = threadIdx.x;
  const int t0 = blockIdx.x * 128;
  if (tid < 128) {
    const int t = t0 + tid;
    float l[EE];
    float maxv = -3.0e38f;
    int arg = 0;
#pragma unroll
    for (int e = 0; e < EE; ++e) {
      l[e] = logits[(size_t)e * N + t];
      if (l[e] > maxv) { maxv = l[e]; arg = e; }  // strict > : first max wins
    }
    float s = 0.f;
#pragma unroll
    for (int e = 0; e < EE; ++e) {
      const float ex = __expf(l[e] - maxv);
      lp[tid][e] = ex;
      s += ex;
    }
    const float inv = 1.0f / s;
    const float w = inv;  // exp(0)/sum
#pragma unroll
    for (int e = 0; e < EE; ++e) lp[tid][e] *= inv;
    dout[t] = w;
    dout[N + t] = (float)arg;
    ws_w[t] = w;
    ws_idx[t] = arg;
    atomicAdd(&counts[arg], 1);
  }
  __syncthreads();
  const int e = tid & 63, q = tid >> 6;
  float ps = 0.f;
  for (int r = 0; r < 32; ++r) ps += lp[q * 32 + r][e];
  psq[q][e] = ps;
  __syncthreads();
  if (tid < 64) {
    const float tot = ((psq[0][tid] + psq[1][tid]) + psq[2][tid]) + psq[3][tid];
    probsum[(size_t)blockIdx.x * EE + tid] = tot;
  }
}

// ---------------- K4: stats, aux loss, mode ----------------
__global__ __launch_bounds__(256) void sr_stats(
    const float* __restrict__ probsum, const int* __restrict__ counts,
    float* __restrict__ dout, int* __restrict__ header,
    int N, int nblocks, int cap)
{
  __shared__ double dq[4][EE];
  __shared__ double mean_s[EE];
  __shared__ int cnt_s[EE];
  const int tid = threadIdx.x;
  const int e = tid & 63, q = tid >> 6;
  const int per = nblocks / 4;
  double ps = 0.0;
  for (int b = q * per; b < (q + 1) * per; ++b)
    ps += (double)probsum[(size_t)b * EE + e];
  dq[q][e] = ps;
  __syncthreads();
  if (tid < 64) {
    const double tot = ((dq[0][tid] + dq[1][tid]) + dq[2][tid]) + dq[3][tid];
    const int cnt = counts[tid];
    dout[2 * N + tid] = (float)cnt;
    mean_s[tid] = tot / (double)N;
    cnt_s[tid] = cnt;
  }
  __syncthreads();
  if (tid == 0) {
    double aux = 0.0;
    int nover = 0, e1 = -1;
    for (int i = 0; i < EE; ++i) {
      aux += ((double)cnt_s[i] / (double)N) * mean_s[i];
      if (cnt_s[i] > cap) { if (nover == 0) e1 = i; ++nover; }
    }
    dout[2 * N + EE] = (float)(aux * (double)EE);
    header[0] = (nover >= 2) ? 2 : nover;
    header[1] = e1;
  }
}

// ---------------- K5: exact top-cap selection (mode==1) ----------------
__device__ __forceinline__ int sr_bsum(int c, int red[][16], int pc, int tid) {
#pragma unroll
  for (int off = 32; off > 0; off >>= 1) c += __shfl_down(c, off, 64);
  if ((tid & 63) == 0) red[pc & 1][tid >> 6] = c;
  __syncthreads();
  int s = 0;
#pragma unroll
  for (int i = 0; i < 16; ++i) s += red[pc & 1][i];
  return s;
}

__global__ __launch_bounds__(1024) void sr_select(
    const float* __restrict__ ws_w, const int* __restrict__ ws_idx,
    int* __restrict__ header, int N, int cap)
{
  __shared__ int red[2][16];
  const int tid = threadIdx.x;
  const int mode = header[0];
  if (mode != 1) {
    if (tid == 0) { header[2] = 0; header[3] = N; }
    return;
  }
  const int e1 = header[1];
  unsigned mb[16];  // PER = N/1024 = 16, cached in VGPRs
  const int PER = N / 1024;
  for (int r = 0; r < 16; ++r) {
    unsigned b = 0u;
    if (r < PER) {
      const int i = tid + r * 1024;
      if (ws_idx[i] == e1) b = __float_as_uint(ws_w[i]);
    }
    mb[r] = b;
  }
  int pc = 0;
  // w = 1/softmax_sum in [1/64, 1): search bits in [0x3C000000, 0x3F800000)
  unsigned lo = 0x3C000000u, hi = 0x3F800000u;
  while (hi - lo > 1u) {
    const unsigned mid = lo + ((hi - lo) >> 1);
    int c = 0;
#pragma unroll
    for (int r = 0; r < 16; ++r) c += (mb[r] >= mid);
    const int tot = sr_bsum(c, red, pc++, tid);
    if (tot >= cap) lo = mid; else hi = mid;
  }
  int cge = 0, cgt = 0;
#pragma unroll
  for (int r = 0; r < 16; ++r) {
    cge += (mb[r] >= lo);
    cgt += (mb[r] > lo);
  }
  const int tot_ge = sr_bsum(cge, red, pc++, tid);
  const int tot_gt = sr_bsum(cgt, red, pc++, tid);
  const int quota = cap - tot_gt;
  int idx_thr = N - 1;
  if (tot_ge - tot_gt > quota) {
    // tie at tau: keep the quota lowest-index equals (lax.top_k tie-break)
    int l2 = -1, h2 = N - 1;
    while (h2 - l2 > 1) {
      const int mid = (l2 + h2) >> 1;
      int c = 0;
#pragma unroll
      for (int r = 0; r < 16; ++r) {
        const int i = tid + r * 1024;
        c += (mb[r] == lo && mb[r] != 0u && i <= mid) ? 1 : 0;
      }
      const int tot = sr_bsum(c, red, pc++, tid);
      if (tot >= quota) h2 = mid; else l2 = mid;
    }
    idx_thr = h2;
  }
  if (tid == 0) { header[2] = (int)lo; header[3] = idx_thr; }
}

// ---------------- K6: apply capacity filter ----------------
__global__ __launch_bounds__(256) void sr_apply(
    const float* __restrict__ ws_w, const int* __restrict__ ws_idx,
    const int* __restrict__ header, float* __restrict__ dout, int N)
{
  const int i = blockIdx.x * 256 + threadIdx.x;
  if (i >= N) return;
  const int mode = header[0];
  const float w = ws_w[i];
  float out = w;
  if (mode == 2) {
    out = 0.f;
  } else if (mode == 1) {
    const int e1 = header[1];
    const unsigned tau = (unsigned)header[2];
    const int ithr = header[3];
    const unsigned b = __float_as_uint(w);
    const bool keep = (ws_idx[i] == e1) && (b > tau || (b == tau && i <= ithr));
    out = keep ? w : 0.f;
  }
  dout[i] = out;
}

// ---------------- launch ----------------
extern "C" void kernel_launch(void* const* d_in, const int* in_sizes, int n_in,
                              void* d_out, int out_size, void* d_ws, size_t ws_size,
                              hipStream_t stream)
{
  const float* x = (const float*)d_in[0];
  const float* wg = (const float*)d_in[1];
  const int N = in_sizes[0] / DD;  // 16384
  float* dout = (float*)d_out;
  float* wsf = (float*)d_ws;

  // ws layout (floats):
  // [ws_w N][ws_idx N][counts 64][probsum (N/128)*64][header 16][logits EE*N][partial ...]
  float* ws_w = wsf;
  int* ws_idx = (int*)(wsf + N);
  int* counts = (int*)(wsf + 2 * (size_t)N);
  float* probsum = wsf + 2 * (size_t)N + EE;
  const int nblocks_sm = N / 128;
  int* header = (int*)(wsf + 2 * (size_t)N + EE + (size_t)nblocks_sm * EE);
  float* logits = wsf + 2 * (size_t)N + EE + (size_t)nblocks_sm * EE + 16;
  float* partial = logits + (size_t)EE * N;
  const size_t base_floats = 2 * (size_t)N + EE + (size_t)nblocks_sm * EE + 16 + (size_t)EE * N;

  int ksplit = 8;
  while (ksplit > 1 &&
         (base_floats + (size_t)ksplit * EE * (size_t)N) * sizeof(float) > ws_size)
    ksplit >>= 1;
  const int cap = (int)((double)N * 1.25 / (double)EE);  // 320

  sr_gemm<<<(N / TOKTILE) * ksplit, 256, 0, stream>>>(x, wg, partial, N, ksplit);
  sr_reduce<<<(EE * N / 4 + 255) / 256, 256, 0, stream>>>(partial, logits, counts, N, ksplit);
  sr_softmax<<<N / 128, 256, 0, stream>>>(logits, dout, ws_w, ws_idx, counts, probsum, N);
  sr_stats<<<1, 256, 0, stream>>>(probsum, counts, dout, header, N, nblocks_sm, cap);
  sr_select<<<1, 1024, 0, stream>>>(ws_w, ws_idx, header, N, cap);
  sr_apply<<<(N + 255) / 256, 256, 0, stream>>>(ws_w, ws_idx, header, dout, N);
}